// Round 1
// baseline (1017.260 us; speedup 1.0000x reference)
//
#include <hip/hip_runtime.h>
#include <hip/hip_bf16.h>

#define HDIM 64

// ---------- degree / normalization ----------
__global__ void k_deg(const int* __restrict__ dst, float* __restrict__ deg, int E) {
    int e = blockIdx.x * blockDim.x + threadIdx.x;
    if (e < E) atomicAdd(&deg[dst[e]], 1.0f);
}

__global__ void k_dis(const float* __restrict__ deg, float* __restrict__ dis, int N) {
    int n = blockIdx.x * blockDim.x + threadIdx.x;
    if (n < N) dis[n] = rsqrtf(deg[n] + 1.0f);
}

// ---------- dense GEMM: out[N][64] = in[N][K] @ W[K][64] ----------
template <int K>
__global__ void k_gemm(const float* __restrict__ in, const float* __restrict__ W,
                       float* __restrict__ out, int N) {
    __shared__ float Wl[K * 64];
    for (int i = threadIdx.x; i < K * 64; i += 256) Wl[i] = W[i];
    __syncthreads();
    int col = threadIdx.x & 63;
    int r   = threadIdx.x >> 6;
    int row = blockIdx.x * 4 + r;
    if (row >= N) return;
    const float* ip = in + (size_t)row * K;
    float sum = 0.f;
#pragma unroll
    for (int k = 0; k < K; k += 4) {
        float4 a = *reinterpret_cast<const float4*>(ip + k);
        sum += a.x * Wl[(k + 0) * 64 + col];
        sum += a.y * Wl[(k + 1) * 64 + col];
        sum += a.z * Wl[(k + 2) * 64 + col];
        sum += a.w * Wl[(k + 3) * 64 + col];
    }
    out[(size_t)row * 64 + col] = sum;
}

// ---------- edge scatter: agg[dst] += h[src] * dis[src]*dis[dst] ----------
__global__ void k_edge(const int* __restrict__ src, const int* __restrict__ dst,
                       const float* __restrict__ dis, const float* __restrict__ h,
                       float* __restrict__ agg, int E) {
    int e    = blockIdx.x * 4 + (threadIdx.x >> 6);
    int lane = threadIdx.x & 63;
    if (e >= E) return;
    int s = src[e], d = dst[e];
    float norm = dis[s] * dis[d];
    float v = h[(size_t)s * 64 + lane] * norm;
    atomicAdd(&agg[(size_t)d * 64 + lane], v);
}

// ---------- self-loop + bias, accumulate BN stats ----------
__global__ void k_selfstats(const float* __restrict__ h, const float* __restrict__ dis,
                            const float* __restrict__ b, float* __restrict__ z,
                            float* __restrict__ stats, int N) {
    int col  = threadIdx.x & 63;
    int rgrp = threadIdx.x >> 6;
    float psum = 0.f, psq = 0.f;
    for (int n = blockIdx.x * 4 + rgrp; n < N; n += gridDim.x * 4) {
        float d  = dis[n];
        float v  = z[(size_t)n * 64 + col] + h[(size_t)n * 64 + col] * (d * d) + b[col];
        z[(size_t)n * 64 + col] = v;
        psum += v;
        psq  += v * v;
    }
    __shared__ float ssum[256], ssq[256];
    ssum[threadIdx.x] = psum;
    ssq[threadIdx.x]  = psq;
    __syncthreads();
    if (threadIdx.x < 64) {
        float s = ssum[threadIdx.x] + ssum[64 + threadIdx.x] + ssum[128 + threadIdx.x] + ssum[192 + threadIdx.x];
        float q = ssq[threadIdx.x] + ssq[64 + threadIdx.x] + ssq[128 + threadIdx.x] + ssq[192 + threadIdx.x];
        atomicAdd(&stats[threadIdx.x], s);
        atomicAdd(&stats[64 + threadIdx.x], q);
    }
}

// ---------- finalize BN scale/shift ----------
__global__ void k_bnfin(const float* __restrict__ stats, const float* __restrict__ g,
                        const float* __restrict__ be, float* __restrict__ scsh, float invN) {
    int c = threadIdx.x;  // 64 threads
    float mu  = stats[c] * invN;
    float var = stats[64 + c] * invN - mu * mu;
    float rs  = rsqrtf(var + 1e-5f);
    float sc  = g[c] * rs;
    scsh[c]      = sc;
    scsh[64 + c] = be[c] - mu * sc;
}

// ---------- normalize + (residual) + relu ----------
__global__ void k_norm(const float* __restrict__ z, const float* __restrict__ scsh,
                       const float* __restrict__ res, float* __restrict__ out, int total) {
    int i = blockIdx.x * blockDim.x + threadIdx.x;
    if (i >= total) return;
    int c = i & 63;
    float v = z[i] * scsh[c] + scsh[64 + c];
    if (res) v += res[i];
    out[i] = fmaxf(v, 0.f);
}

// ---------- global mean pool (accumulate) ----------
__global__ void k_pool(const float* __restrict__ h, const int* __restrict__ batch,
                       float* __restrict__ sums, float* __restrict__ cnt, int N) {
    int n    = blockIdx.x * 4 + (threadIdx.x >> 6);
    int lane = threadIdx.x & 63;
    if (n >= N) return;
    int g = batch[n];
    atomicAdd(&sums[(size_t)g * 64 + lane], h[(size_t)n * 64 + lane]);
    if (lane == 0) atomicAdd(&cnt[g], 1.0f);
}

// ---------- FF branch + fusion head: one block per graph ----------
__global__ void k_head(const float* __restrict__ sigma, const float* __restrict__ Wf1,
                       const float* __restrict__ bf1, const float* __restrict__ Wf2,
                       const float* __restrict__ bf2, const float* __restrict__ Wfu,
                       const float* __restrict__ bfu, const float* __restrict__ sums,
                       const float* __restrict__ cnt, float* __restrict__ out) {
    int g = blockIdx.x;
    int t = threadIdx.x;  // 128 threads
    __shared__ float srow[64], f1[128], f2[64];
    if (t < 64) srow[t] = sigma[(size_t)g * 64 + t];
    __syncthreads();
    {
        float acc = bf1[t];
        for (int s = 0; s < 64; ++s) acc += srow[s] * Wf1[s * 128 + t];
        f1[t] = fmaxf(acc, 0.f);
    }
    __syncthreads();
    if (t < 64) {
        float a2 = bf2[t];
        for (int k = 0; k < 128; ++k) a2 += f1[k] * Wf2[k * 64 + t];
        f2[t] = fmaxf(a2, 0.f);
    }
    __syncthreads();
    if (t < 64) {
        float inv    = 1.0f / fmaxf(cnt[g], 1.0f);
        float pooled = sums[(size_t)g * 64 + t] * inv;
        float contrib = pooled * Wfu[t] + f2[t] * Wfu[64 + t];
#pragma unroll
        for (int o = 32; o > 0; o >>= 1) contrib += __shfl_down(contrib, o);
        if (t == 0) out[g] = contrib + bfu[0];
    }
}

extern "C" void kernel_launch(void* const* d_in, const int* in_sizes, int n_in,
                              void* d_out, int out_size, void* d_ws, size_t ws_size,
                              hipStream_t stream) {
    const float* x     = (const float*)d_in[0];
    const int*   ei    = (const int*)d_in[1];
    const int*   batch = (const int*)d_in[2];
    const float* sigma = (const float*)d_in[3];
    const float* W1 = (const float*)d_in[4];  const float* b1 = (const float*)d_in[5];
    const float* g1 = (const float*)d_in[6];  const float* be1 = (const float*)d_in[7];
    const float* W2 = (const float*)d_in[8];  const float* b2 = (const float*)d_in[9];
    const float* g2 = (const float*)d_in[10]; const float* be2 = (const float*)d_in[11];
    const float* W3 = (const float*)d_in[12]; const float* b3 = (const float*)d_in[13];
    const float* g3 = (const float*)d_in[14]; const float* be3 = (const float*)d_in[15];
    const float* Wf1 = (const float*)d_in[16]; const float* bf1 = (const float*)d_in[17];
    const float* Wf2 = (const float*)d_in[18]; const float* bf2 = (const float*)d_in[19];
    const float* Wfu = (const float*)d_in[20]; const float* bfu = (const float*)d_in[21];

    const int N = in_sizes[0] / 128;
    const int E = in_sizes[1] / 2;
    const int G = in_sizes[3] / 64;
    const int* src = ei;
    const int* dst = ei + E;

    float* ws   = (float*)d_ws;
    float* bufA = ws;
    float* bufB = bufA + (size_t)N * 64;
    float* bufC = bufB + (size_t)N * 64;
    float* deg  = bufC + (size_t)N * 64;
    float* dis  = deg + N;
    float* stats = dis + N;
    float* scsh  = stats + 128;
    float* psums = scsh + 128;
    float* pcnt  = psums + (size_t)G * 64;

    const float invN = 1.0f / (float)N;
    const int totNH  = N * 64;

    // degrees
    hipMemsetAsync(deg, 0, N * sizeof(float), stream);
    k_deg<<<(E + 255) / 256, 256, 0, stream>>>(dst, deg, E);
    k_dis<<<(N + 255) / 256, 256, 0, stream>>>(deg, dis, N);

    // ---- layer 1 ----
    k_gemm<128><<<(N + 3) / 4, 256, 0, stream>>>(x, W1, bufA, N);
    hipMemsetAsync(bufB, 0, (size_t)totNH * sizeof(float), stream);
    k_edge<<<(E + 3) / 4, 256, 0, stream>>>(src, dst, dis, bufA, bufB, E);
    hipMemsetAsync(stats, 0, 128 * sizeof(float), stream);
    k_selfstats<<<1024, 256, 0, stream>>>(bufA, dis, b1, bufB, stats, N);
    k_bnfin<<<1, 64, 0, stream>>>(stats, g1, be1, scsh, invN);
    k_norm<<<(totNH + 255) / 256, 256, 0, stream>>>(bufB, scsh, nullptr, bufC, totNH);

    // ---- layer 2 (residual = bufC) ----
    k_gemm<64><<<(N + 3) / 4, 256, 0, stream>>>(bufC, W2, bufA, N);
    hipMemsetAsync(bufB, 0, (size_t)totNH * sizeof(float), stream);
    k_edge<<<(E + 3) / 4, 256, 0, stream>>>(src, dst, dis, bufA, bufB, E);
    hipMemsetAsync(stats, 0, 128 * sizeof(float), stream);
    k_selfstats<<<1024, 256, 0, stream>>>(bufA, dis, b2, bufB, stats, N);
    k_bnfin<<<1, 64, 0, stream>>>(stats, g2, be2, scsh, invN);
    k_norm<<<(totNH + 255) / 256, 256, 0, stream>>>(bufB, scsh, bufC, bufA, totNH);

    // ---- layer 3 ----
    k_gemm<64><<<(N + 3) / 4, 256, 0, stream>>>(bufA, W3, bufC, N);
    hipMemsetAsync(bufB, 0, (size_t)totNH * sizeof(float), stream);
    k_edge<<<(E + 3) / 4, 256, 0, stream>>>(src, dst, dis, bufC, bufB, E);
    hipMemsetAsync(stats, 0, 128 * sizeof(float), stream);
    k_selfstats<<<1024, 256, 0, stream>>>(bufC, dis, b3, bufB, stats, N);
    k_bnfin<<<1, 64, 0, stream>>>(stats, g3, be3, scsh, invN);
    k_norm<<<(totNH + 255) / 256, 256, 0, stream>>>(bufB, scsh, nullptr, bufC, totNH);

    // ---- pooling ----
    hipMemsetAsync(psums, 0, (size_t)G * 64 * sizeof(float), stream);
    hipMemsetAsync(pcnt, 0, G * sizeof(float), stream);
    k_pool<<<(N + 3) / 4, 256, 0, stream>>>(bufC, batch, psums, pcnt, N);

    // ---- head ----
    k_head<<<G, 128, 0, stream>>>(sigma, Wf1, bf1, Wf2, bf2, Wfu, bfu, psums, pcnt, (float*)d_out);
}

// Round 2
// 553.600 us; speedup vs baseline: 1.8375x; 1.8375x over previous
//
#include <hip/hip_runtime.h>
#include <hip/hip_bf16.h>

// ---------- CSR build ----------
__global__ void k_hist(const int* __restrict__ dst, int* __restrict__ cnt, int E) {
    int e = blockIdx.x * blockDim.x + threadIdx.x;
    if (e < E) atomicAdd(&cnt[dst[e]], 1);
}

__global__ void k_dis(const int* __restrict__ cnt, float* __restrict__ dis, int N) {
    int n = blockIdx.x * blockDim.x + threadIdx.x;
    if (n < N) dis[n] = rsqrtf((float)cnt[n] + 1.0f);
}

// single-block exclusive scan over cnt -> row_ptr (N up to ~1M fine)
__global__ void k_scan(const int* __restrict__ cnt, int* __restrict__ row_ptr, int N) {
    const int T = 1024;
    int t = threadIdx.x;
    int chunk = (N + T - 1) / T;
    int begin = t * chunk;
    int end = begin + chunk; if (end > N) end = N;
    int s = 0;
    for (int i = begin; i < end; ++i) s += cnt[i];
    __shared__ int part[T];
    part[t] = s;
    __syncthreads();
    for (int off = 1; off < T; off <<= 1) {
        int v = (t >= off) ? part[t - off] : 0;
        __syncthreads();
        part[t] += v;
        __syncthreads();
    }
    int excl = (t == 0) ? 0 : part[t - 1];
    for (int i = begin; i < end; ++i) { row_ptr[i] = excl; excl += cnt[i]; }
}

__global__ void k_fill(const int* __restrict__ src, const int* __restrict__ dst,
                       const int* __restrict__ row_ptr, int* __restrict__ cursor,
                       int* __restrict__ csr_src, int E) {
    int e = blockIdx.x * blockDim.x + threadIdx.x;
    if (e < E) {
        int d = dst[e];
        int pos = row_ptr[d] + atomicAdd(&cursor[d], 1);
        csr_src[pos] = src[e];
    }
}

// ---------- dense GEMM: out[N][64] = (in[N][K] @ W[K][64]) * dis[row] ----------
template <int K>
__global__ void k_gemm(const float* __restrict__ in, const float* __restrict__ W,
                       const float* __restrict__ dis, float* __restrict__ out, int N) {
    __shared__ float Wl[K * 64];
    for (int i = threadIdx.x; i < K * 64; i += 256) Wl[i] = W[i];
    __syncthreads();
    int col = threadIdx.x & 63;
    int r   = threadIdx.x >> 6;
    int row = blockIdx.x * 4 + r;
    if (row >= N) return;
    const float* ip = in + (size_t)row * K;
    float sum = 0.f;
#pragma unroll
    for (int k = 0; k < K; k += 4) {
        float4 a = *reinterpret_cast<const float4*>(ip + k);
        sum += a.x * Wl[(k + 0) * 64 + col];
        sum += a.y * Wl[(k + 1) * 64 + col];
        sum += a.z * Wl[(k + 2) * 64 + col];
        sum += a.w * Wl[(k + 3) * 64 + col];
    }
    out[(size_t)row * 64 + col] = sum * dis[row];
}

// ---------- CSR gather + self-loop + bias + BN stats ----------
// z[n] = dis[n] * (sum_{s in in(n)} hs[s] + hs[n]) + b ;  hs = h * dis
__global__ void k_gather(const int* __restrict__ row_ptr, const int* __restrict__ cnt,
                         const int* __restrict__ csr_src, const float* __restrict__ dis,
                         const float* __restrict__ hs, const float* __restrict__ b,
                         float* __restrict__ z, float* __restrict__ stats, int N) {
    int lane = threadIdx.x & 63;
    int w    = threadIdx.x >> 6;
    float psum = 0.f, psq = 0.f;
    for (int n = blockIdx.x * 4 + w; n < N; n += gridDim.x * 4) {
        int start = row_ptr[n];
        int c     = cnt[n];
        float acc = hs[(size_t)n * 64 + lane];
        int j = 0;
        for (; j + 3 < c; j += 4) {
            int s0 = csr_src[start + j];
            int s1 = csr_src[start + j + 1];
            int s2 = csr_src[start + j + 2];
            int s3 = csr_src[start + j + 3];
            acc += hs[(size_t)s0 * 64 + lane];
            acc += hs[(size_t)s1 * 64 + lane];
            acc += hs[(size_t)s2 * 64 + lane];
            acc += hs[(size_t)s3 * 64 + lane];
        }
        for (; j < c; ++j) acc += hs[(size_t)csr_src[start + j] * 64 + lane];
        float v = acc * dis[n] + b[lane];
        z[(size_t)n * 64 + lane] = v;
        psum += v;
        psq  += v * v;
    }
    __shared__ float ssum[256], ssq[256];
    ssum[threadIdx.x] = psum;
    ssq[threadIdx.x]  = psq;
    __syncthreads();
    if (threadIdx.x < 64) {
        float s = ssum[threadIdx.x] + ssum[64 + threadIdx.x] + ssum[128 + threadIdx.x] + ssum[192 + threadIdx.x];
        float q = ssq[threadIdx.x] + ssq[64 + threadIdx.x] + ssq[128 + threadIdx.x] + ssq[192 + threadIdx.x];
        atomicAdd(&stats[threadIdx.x], s);
        atomicAdd(&stats[64 + threadIdx.x], q);
    }
}

// ---------- finalize BN scale/shift ----------
__global__ void k_bnfin(const float* __restrict__ stats, const float* __restrict__ g,
                        const float* __restrict__ be, float* __restrict__ scsh, float invN) {
    int c = threadIdx.x;  // 64 threads
    float mu  = stats[c] * invN;
    float var = stats[64 + c] * invN - mu * mu;
    float rs  = rsqrtf(var + 1e-5f);
    float sc  = g[c] * rs;
    scsh[c]      = sc;
    scsh[64 + c] = be[c] - mu * sc;
}

// ---------- normalize + (residual) + relu ----------
__global__ void k_norm(const float* __restrict__ z, const float* __restrict__ scsh,
                       const float* __restrict__ res, float* __restrict__ out, int total) {
    int i = blockIdx.x * blockDim.x + threadIdx.x;
    if (i >= total) return;
    int c = i & 63;
    float v = z[i] * scsh[c] + scsh[64 + c];
    if (res) v += res[i];
    out[i] = fmaxf(v, 0.f);
}

// ---------- layer-3 normalize + relu + segmented pool (batch sorted) ----------
__global__ void k_norm_pool(const float* __restrict__ z, const float* __restrict__ scsh,
                            const int* __restrict__ batch, float* __restrict__ psums,
                            float* __restrict__ pcnt, int N, int per) {
    int lane = threadIdx.x & 63;
    int wave = (blockIdx.x * blockDim.x + threadIdx.x) >> 6;
    int begin = wave * per;
    if (begin >= N) return;
    int end = begin + per; if (end > N) end = N;
    float sc = scsh[lane], sh = scsh[64 + lane];
    int   cur = batch[begin];
    float run = 0.f;
    int   crun = 0;
    for (int n = begin; n < end; ++n) {
        int g = batch[n];
        if (g != cur) {
            atomicAdd(&psums[(size_t)cur * 64 + lane], run);
            if (lane == 0) atomicAdd(&pcnt[cur], (float)crun);
            run = 0.f; crun = 0; cur = g;
        }
        float v = fmaxf(z[(size_t)n * 64 + lane] * sc + sh, 0.f);
        run += v; crun++;
    }
    atomicAdd(&psums[(size_t)cur * 64 + lane], run);
    if (lane == 0) atomicAdd(&pcnt[cur], (float)crun);
}

// ---------- FF branch + fusion head: one block per graph ----------
__global__ void k_head(const float* __restrict__ sigma, const float* __restrict__ Wf1,
                       const float* __restrict__ bf1, const float* __restrict__ Wf2,
                       const float* __restrict__ bf2, const float* __restrict__ Wfu,
                       const float* __restrict__ bfu, const float* __restrict__ sums,
                       const float* __restrict__ cnt, float* __restrict__ out) {
    int g = blockIdx.x;
    int t = threadIdx.x;  // 128 threads
    __shared__ float srow[64], f1[128], f2[64];
    if (t < 64) srow[t] = sigma[(size_t)g * 64 + t];
    __syncthreads();
    {
        float acc = bf1[t];
        for (int s = 0; s < 64; ++s) acc += srow[s] * Wf1[s * 128 + t];
        f1[t] = fmaxf(acc, 0.f);
    }
    __syncthreads();
    if (t < 64) {
        float a2 = bf2[t];
        for (int k = 0; k < 128; ++k) a2 += f1[k] * Wf2[k * 64 + t];
        f2[t] = fmaxf(a2, 0.f);
    }
    __syncthreads();
    if (t < 64) {
        float inv    = 1.0f / fmaxf(cnt[g], 1.0f);
        float pooled = sums[(size_t)g * 64 + t] * inv;
        float contrib = pooled * Wfu[t] + f2[t] * Wfu[64 + t];
#pragma unroll
        for (int o = 32; o > 0; o >>= 1) contrib += __shfl_down(contrib, o);
        if (t == 0) out[g] = contrib + bfu[0];
    }
}

extern "C" void kernel_launch(void* const* d_in, const int* in_sizes, int n_in,
                              void* d_out, int out_size, void* d_ws, size_t ws_size,
                              hipStream_t stream) {
    const float* x     = (const float*)d_in[0];
    const int*   ei    = (const int*)d_in[1];
    const int*   batch = (const int*)d_in[2];
    const float* sigma = (const float*)d_in[3];
    const float* W1 = (const float*)d_in[4];  const float* b1 = (const float*)d_in[5];
    const float* g1 = (const float*)d_in[6];  const float* be1 = (const float*)d_in[7];
    const float* W2 = (const float*)d_in[8];  const float* b2 = (const float*)d_in[9];
    const float* g2 = (const float*)d_in[10]; const float* be2 = (const float*)d_in[11];
    const float* W3 = (const float*)d_in[12]; const float* b3 = (const float*)d_in[13];
    const float* g3 = (const float*)d_in[14]; const float* be3 = (const float*)d_in[15];
    const float* Wf1 = (const float*)d_in[16]; const float* bf1 = (const float*)d_in[17];
    const float* Wf2 = (const float*)d_in[18]; const float* bf2 = (const float*)d_in[19];
    const float* Wfu = (const float*)d_in[20]; const float* bfu = (const float*)d_in[21];

    const int N = in_sizes[0] / 128;
    const int E = in_sizes[1] / 2;
    const int G = in_sizes[3] / 64;
    const int* src = ei;
    const int* dst = ei + E;

    float* ws   = (float*)d_ws;
    float* bufA = ws;                       // hs (pre-scaled gemm out)
    float* bufB = bufA + (size_t)N * 64;    // z
    float* bufC = bufB + (size_t)N * 64;    // h (activations)
    float* dis  = bufC + (size_t)N * 64;
    float* stats = dis + N;
    float* scsh  = stats + 128;
    float* psums = scsh + 128;
    float* pcnt  = psums + (size_t)G * 64;
    int* cnt     = (int*)(pcnt + G);
    int* row_ptr = cnt + N;
    int* cursor  = row_ptr + N;
    int* csr_src = cursor + N;

    const float invN = 1.0f / (float)N;
    const int totNH  = N * 64;

    // ---- CSR build + degrees ----
    hipMemsetAsync(cnt, 0, N * sizeof(int), stream);
    hipMemsetAsync(cursor, 0, N * sizeof(int), stream);
    k_hist<<<(E + 255) / 256, 256, 0, stream>>>(dst, cnt, E);
    k_dis<<<(N + 255) / 256, 256, 0, stream>>>(cnt, dis, N);
    k_scan<<<1, 1024, 0, stream>>>(cnt, row_ptr, N);
    k_fill<<<(E + 255) / 256, 256, 0, stream>>>(src, dst, row_ptr, cursor, csr_src, E);

    // ---- layer 1 ----
    k_gemm<128><<<(N + 3) / 4, 256, 0, stream>>>(x, W1, dis, bufA, N);
    hipMemsetAsync(stats, 0, 128 * sizeof(float), stream);
    k_gather<<<1024, 256, 0, stream>>>(row_ptr, cnt, csr_src, dis, bufA, b1, bufB, stats, N);
    k_bnfin<<<1, 64, 0, stream>>>(stats, g1, be1, scsh, invN);
    k_norm<<<(totNH + 255) / 256, 256, 0, stream>>>(bufB, scsh, nullptr, bufC, totNH);

    // ---- layer 2 (residual = bufC) ----
    k_gemm<64><<<(N + 3) / 4, 256, 0, stream>>>(bufC, W2, dis, bufA, N);
    hipMemsetAsync(stats, 0, 128 * sizeof(float), stream);
    k_gather<<<1024, 256, 0, stream>>>(row_ptr, cnt, csr_src, dis, bufA, b2, bufB, stats, N);
    k_bnfin<<<1, 64, 0, stream>>>(stats, g2, be2, scsh, invN);
    k_norm<<<(totNH + 255) / 256, 256, 0, stream>>>(bufB, scsh, bufC, bufA, totNH);  // h2 -> bufA

    // ---- layer 3 ----
    k_gemm<64><<<(N + 3) / 4, 256, 0, stream>>>(bufA, W3, dis, bufC, N);            // hs3 -> bufC
    hipMemsetAsync(stats, 0, 128 * sizeof(float), stream);
    k_gather<<<1024, 256, 0, stream>>>(row_ptr, cnt, csr_src, dis, bufC, b3, bufB, stats, N);
    k_bnfin<<<1, 64, 0, stream>>>(stats, g3, be3, scsh, invN);

    // ---- fused normalize + relu + pool ----
    hipMemsetAsync(psums, 0, (size_t)G * 64 * sizeof(float), stream);
    hipMemsetAsync(pcnt, 0, G * sizeof(float), stream);
    {
        const int waves = 4096;  // 1024 blocks x 4 waves
        int per = (N + waves - 1) / waves;
        k_norm_pool<<<1024, 256, 0, stream>>>(bufB, scsh, batch, psums, pcnt, N, per);
    }

    // ---- head ----
    k_head<<<G, 128, 0, stream>>>(sigma, Wf1, bf1, Wf2, bf2, Wfu, bfu, psums, pcnt, (float*)d_out);
}

// Round 3
// 489.384 us; speedup vs baseline: 2.0787x; 1.1312x over previous
//
#include <hip/hip_runtime.h>
#include <hip/hip_bf16.h>

// ---------- CSR build ----------
__global__ void k_hist(const int* __restrict__ dst, int* __restrict__ cnt, int E) {
    int e = blockIdx.x * blockDim.x + threadIdx.x;
    if (e < E) atomicAdd(&cnt[dst[e]], 1);
}

// ---------- hierarchical exclusive scan: A (block sums), B (scan partials), C (local scan + dis) ----------
__global__ void k_scanA(const int* __restrict__ cnt, int* __restrict__ bsum, int N) {
    __shared__ int sh[256];
    int i = blockIdx.x * 256 + threadIdx.x;
    sh[threadIdx.x] = (i < N) ? cnt[i] : 0;
    __syncthreads();
    for (int off = 128; off > 0; off >>= 1) {
        if (threadIdx.x < off) sh[threadIdx.x] += sh[threadIdx.x + off];
        __syncthreads();
    }
    if (threadIdx.x == 0) bsum[blockIdx.x] = sh[0];
}

__global__ void k_scanB(int* __restrict__ bsum, int nb) {
    __shared__ int sh[1024];
    int t = threadIdx.x;
    sh[t] = (t < nb) ? bsum[t] : 0;
    __syncthreads();
    for (int off = 1; off < 1024; off <<= 1) {
        int v = (t >= off) ? sh[t - off] : 0;
        __syncthreads();
        sh[t] += v;
        __syncthreads();
    }
    if (t < nb) bsum[t] = (t == 0) ? 0 : sh[t - 1];  // exclusive block offsets
}

__global__ void k_scanC(const int* __restrict__ cnt, const int* __restrict__ boff,
                        int* __restrict__ row_ptr, float* __restrict__ dis, int N) {
    __shared__ int sh[256];
    int i = blockIdx.x * 256 + threadIdx.x;
    int v = (i < N) ? cnt[i] : 0;
    sh[threadIdx.x] = v;
    __syncthreads();
    for (int off = 1; off < 256; off <<= 1) {
        int u = (threadIdx.x >= off) ? sh[threadIdx.x - off] : 0;
        __syncthreads();
        sh[threadIdx.x] += u;
        __syncthreads();
    }
    if (i < N) {
        row_ptr[i] = sh[threadIdx.x] - v + boff[blockIdx.x];
        dis[i] = rsqrtf((float)v + 1.0f);
    }
}

__global__ void k_fill(const int* __restrict__ src, const int* __restrict__ dst,
                       const int* __restrict__ row_ptr, int* __restrict__ cursor,
                       int* __restrict__ csr_src, int E) {
    int e = blockIdx.x * blockDim.x + threadIdx.x;
    if (e < E) {
        int d = dst[e];
        int pos = row_ptr[d] + atomicAdd(&cursor[d], 1);
        csr_src[pos] = src[e];
    }
}

// ---------- dense GEMM: out[N][64] = (in[N][K] @ W[K][64]) * dis[row] ----------
template <int K>
__global__ void k_gemm(const float* __restrict__ in, const float* __restrict__ W,
                       const float* __restrict__ dis, float* __restrict__ out, int N) {
    __shared__ float Wl[K * 64];
    for (int i = threadIdx.x; i < K * 64; i += 256) Wl[i] = W[i];
    __syncthreads();
    int col = threadIdx.x & 63;
    int r   = threadIdx.x >> 6;
    int row = blockIdx.x * 4 + r;
    if (row >= N) return;
    const float* ip = in + (size_t)row * K;
    float sum = 0.f;
#pragma unroll
    for (int k = 0; k < K; k += 4) {
        float4 a = *reinterpret_cast<const float4*>(ip + k);
        sum += a.x * Wl[(k + 0) * 64 + col];
        sum += a.y * Wl[(k + 1) * 64 + col];
        sum += a.z * Wl[(k + 2) * 64 + col];
        sum += a.w * Wl[(k + 3) * 64 + col];
    }
    out[(size_t)row * 64 + col] = sum * dis[row];
}

// ---------- CSR gather + self-loop + bias + BN stats ----------
// z[n] = dis[n] * (sum_{s in in(n)} hs[s] + hs[n]) + b ;  hs = h * dis
__global__ void k_gather(const int* __restrict__ row_ptr, const int* __restrict__ cnt,
                         const int* __restrict__ csr_src, const float* __restrict__ dis,
                         const float* __restrict__ hs, const float* __restrict__ b,
                         float* __restrict__ z, float* __restrict__ stats, int N) {
    int lane = threadIdx.x & 63;
    int w    = threadIdx.x >> 6;
    float psum = 0.f, psq = 0.f;
    for (int n = blockIdx.x * 4 + w; n < N; n += gridDim.x * 4) {
        int start = row_ptr[n];
        int c     = cnt[n];
        float acc = hs[(size_t)n * 64 + lane];
        int j = 0;
        for (; j + 3 < c; j += 4) {
            int s0 = csr_src[start + j];
            int s1 = csr_src[start + j + 1];
            int s2 = csr_src[start + j + 2];
            int s3 = csr_src[start + j + 3];
            acc += hs[(size_t)s0 * 64 + lane];
            acc += hs[(size_t)s1 * 64 + lane];
            acc += hs[(size_t)s2 * 64 + lane];
            acc += hs[(size_t)s3 * 64 + lane];
        }
        for (; j < c; ++j) acc += hs[(size_t)csr_src[start + j] * 64 + lane];
        float v = acc * dis[n] + b[lane];
        z[(size_t)n * 64 + lane] = v;
        psum += v;
        psq  += v * v;
    }
    __shared__ float ssum[256], ssq[256];
    ssum[threadIdx.x] = psum;
    ssq[threadIdx.x]  = psq;
    __syncthreads();
    if (threadIdx.x < 64) {
        float s = ssum[threadIdx.x] + ssum[64 + threadIdx.x] + ssum[128 + threadIdx.x] + ssum[192 + threadIdx.x];
        float q = ssq[threadIdx.x] + ssq[64 + threadIdx.x] + ssq[128 + threadIdx.x] + ssq[192 + threadIdx.x];
        atomicAdd(&stats[threadIdx.x], s);
        atomicAdd(&stats[64 + threadIdx.x], q);
    }
}

// ---------- finalize BN scale/shift ----------
__global__ void k_bnfin(const float* __restrict__ stats, const float* __restrict__ g,
                        const float* __restrict__ be, float* __restrict__ scsh, float invN) {
    int c = threadIdx.x;  // 64 threads
    float mu  = stats[c] * invN;
    float var = stats[64 + c] * invN - mu * mu;
    float rs  = rsqrtf(var + 1e-5f);
    float sc  = g[c] * rs;
    scsh[c]      = sc;
    scsh[64 + c] = be[c] - mu * sc;
}

// ---------- normalize + (residual) + relu ----------
__global__ void k_norm(const float* __restrict__ z, const float* __restrict__ scsh,
                       const float* __restrict__ res, float* __restrict__ out, int total) {
    int i = blockIdx.x * blockDim.x + threadIdx.x;
    if (i >= total) return;
    int c = i & 63;
    float v = z[i] * scsh[c] + scsh[64 + c];
    if (res) v += res[i];
    out[i] = fmaxf(v, 0.f);
}

// ---------- layer-3 normalize + relu + segmented pool (batch sorted) ----------
__global__ void k_norm_pool(const float* __restrict__ z, const float* __restrict__ scsh,
                            const int* __restrict__ batch, float* __restrict__ psums,
                            float* __restrict__ pcnt, int N, int per) {
    int lane = threadIdx.x & 63;
    int wave = (blockIdx.x * blockDim.x + threadIdx.x) >> 6;
    int begin = wave * per;
    if (begin >= N) return;
    int end = begin + per; if (end > N) end = N;
    float sc = scsh[lane], sh = scsh[64 + lane];
    int   cur = batch[begin];
    float run = 0.f;
    int   crun = 0;
    for (int n = begin; n < end; ++n) {
        int g = batch[n];
        if (g != cur) {
            atomicAdd(&psums[(size_t)cur * 64 + lane], run);
            if (lane == 0) atomicAdd(&pcnt[cur], (float)crun);
            run = 0.f; crun = 0; cur = g;
        }
        float v = fmaxf(z[(size_t)n * 64 + lane] * sc + sh, 0.f);
        run += v; crun++;
    }
    atomicAdd(&psums[(size_t)cur * 64 + lane], run);
    if (lane == 0) atomicAdd(&pcnt[cur], (float)crun);
}

// ---------- FF branch + fusion head: one block per graph ----------
__global__ void k_head(const float* __restrict__ sigma, const float* __restrict__ Wf1,
                       const float* __restrict__ bf1, const float* __restrict__ Wf2,
                       const float* __restrict__ bf2, const float* __restrict__ Wfu,
                       const float* __restrict__ bfu, const float* __restrict__ sums,
                       const float* __restrict__ cnt, float* __restrict__ out) {
    int g = blockIdx.x;
    int t = threadIdx.x;  // 128 threads
    __shared__ float srow[64], f1[128], f2[64];
    if (t < 64) srow[t] = sigma[(size_t)g * 64 + t];
    __syncthreads();
    {
        float acc = bf1[t];
        for (int s = 0; s < 64; ++s) acc += srow[s] * Wf1[s * 128 + t];
        f1[t] = fmaxf(acc, 0.f);
    }
    __syncthreads();
    if (t < 64) {
        float a2 = bf2[t];
        for (int k = 0; k < 128; ++k) a2 += f1[k] * Wf2[k * 64 + t];
        f2[t] = fmaxf(a2, 0.f);
    }
    __syncthreads();
    if (t < 64) {
        float inv    = 1.0f / fmaxf(cnt[g], 1.0f);
        float pooled = sums[(size_t)g * 64 + t] * inv;
        float contrib = pooled * Wfu[t] + f2[t] * Wfu[64 + t];
#pragma unroll
        for (int o = 32; o > 0; o >>= 1) contrib += __shfl_down(contrib, o);
        if (t == 0) out[g] = contrib + bfu[0];
    }
}

extern "C" void kernel_launch(void* const* d_in, const int* in_sizes, int n_in,
                              void* d_out, int out_size, void* d_ws, size_t ws_size,
                              hipStream_t stream) {
    const float* x     = (const float*)d_in[0];
    const int*   ei    = (const int*)d_in[1];
    const int*   batch = (const int*)d_in[2];
    const float* sigma = (const float*)d_in[3];
    const float* W1 = (const float*)d_in[4];  const float* b1 = (const float*)d_in[5];
    const float* g1 = (const float*)d_in[6];  const float* be1 = (const float*)d_in[7];
    const float* W2 = (const float*)d_in[8];  const float* b2 = (const float*)d_in[9];
    const float* g2 = (const float*)d_in[10]; const float* be2 = (const float*)d_in[11];
    const float* W3 = (const float*)d_in[12]; const float* b3 = (const float*)d_in[13];
    const float* g3 = (const float*)d_in[14]; const float* be3 = (const float*)d_in[15];
    const float* Wf1 = (const float*)d_in[16]; const float* bf1 = (const float*)d_in[17];
    const float* Wf2 = (const float*)d_in[18]; const float* bf2 = (const float*)d_in[19];
    const float* Wfu = (const float*)d_in[20]; const float* bfu = (const float*)d_in[21];

    const int N = in_sizes[0] / 128;
    const int E = in_sizes[1] / 2;
    const int G = in_sizes[3] / 64;
    const int* src = ei;
    const int* dst = ei + E;

    float* ws   = (float*)d_ws;
    float* bufA = ws;                       // hs (pre-scaled gemm out)
    float* bufB = bufA + (size_t)N * 64;    // z
    float* bufC = bufB + (size_t)N * 64;    // h (activations)
    float* dis  = bufC + (size_t)N * 64;
    float* stats = dis + N;
    float* scsh  = stats + 128;
    float* psums = scsh + 128;
    float* pcnt  = psums + (size_t)G * 64;
    int* cnt     = (int*)(pcnt + G);
    int* row_ptr = cnt + N;
    int* cursor  = row_ptr + N;
    int* bsum    = cursor + N;
    int* csr_src = bsum + 1024;

    const float invN = 1.0f / (float)N;
    const int totNH  = N * 64;
    const int nb     = (N + 255) / 256;

    // ---- CSR build + degrees (hierarchical scan) ----
    hipMemsetAsync(cnt, 0, N * sizeof(int), stream);
    hipMemsetAsync(cursor, 0, N * sizeof(int), stream);
    k_hist<<<(E + 255) / 256, 256, 0, stream>>>(dst, cnt, E);
    k_scanA<<<nb, 256, 0, stream>>>(cnt, bsum, N);
    k_scanB<<<1, 1024, 0, stream>>>(bsum, nb);
    k_scanC<<<nb, 256, 0, stream>>>(cnt, bsum, row_ptr, dis, N);
    k_fill<<<(E + 255) / 256, 256, 0, stream>>>(src, dst, row_ptr, cursor, csr_src, E);

    // ---- layer 1 ----
    k_gemm<128><<<(N + 3) / 4, 256, 0, stream>>>(x, W1, dis, bufA, N);
    hipMemsetAsync(stats, 0, 128 * sizeof(float), stream);
    k_gather<<<1024, 256, 0, stream>>>(row_ptr, cnt, csr_src, dis, bufA, b1, bufB, stats, N);
    k_bnfin<<<1, 64, 0, stream>>>(stats, g1, be1, scsh, invN);
    k_norm<<<(totNH + 255) / 256, 256, 0, stream>>>(bufB, scsh, nullptr, bufC, totNH);

    // ---- layer 2 (residual = bufC) ----
    k_gemm<64><<<(N + 3) / 4, 256, 0, stream>>>(bufC, W2, dis, bufA, N);
    hipMemsetAsync(stats, 0, 128 * sizeof(float), stream);
    k_gather<<<1024, 256, 0, stream>>>(row_ptr, cnt, csr_src, dis, bufA, b2, bufB, stats, N);
    k_bnfin<<<1, 64, 0, stream>>>(stats, g2, be2, scsh, invN);
    k_norm<<<(totNH + 255) / 256, 256, 0, stream>>>(bufB, scsh, bufC, bufA, totNH);  // h2 -> bufA

    // ---- layer 3 ----
    k_gemm<64><<<(N + 3) / 4, 256, 0, stream>>>(bufA, W3, dis, bufC, N);            // hs3 -> bufC
    hipMemsetAsync(stats, 0, 128 * sizeof(float), stream);
    k_gather<<<1024, 256, 0, stream>>>(row_ptr, cnt, csr_src, dis, bufC, b3, bufB, stats, N);
    k_bnfin<<<1, 64, 0, stream>>>(stats, g3, be3, scsh, invN);

    // ---- fused normalize + relu + pool ----
    hipMemsetAsync(psums, 0, (size_t)G * 64 * sizeof(float), stream);
    hipMemsetAsync(pcnt, 0, G * sizeof(float), stream);
    {
        const int waves = 4096;  // 1024 blocks x 4 waves
        int per = (N + waves - 1) / waves;
        k_norm_pool<<<1024, 256, 0, stream>>>(bufB, scsh, batch, psums, pcnt, N, per);
    }

    // ---- head ----
    k_head<<<G, 128, 0, stream>>>(sigma, Wf1, bf1, Wf2, bf2, Wfu, bfu, psums, pcnt, (float*)d_out);
}